// Round 6
// baseline (2315.383 us; speedup 1.0000x reference)
//
#include <hip/hip_runtime.h>
#include <math.h>

#define NB 4
#define NPTS 20000
#define CH 256
#define NS 1024
#define NV 300
#define KC 32

// out offsets (floats)
#define O0 0         // objectness (4,2,20000)
#define O1 160000    // graspness (4,20000)
#define O2 240000    // graspable_xyz (4,1024,3)
#define O3 252288    // graspable_inds (4,1024)
#define O4 256384    // graspable_features (4,256,1024)
#define O5 1304960   // fp2_graspness (4,1024)
#define O6 1309056   // vp_xyz (4,1024,3)
#define O7 1321344   // top_view_inds (4,1024)
#define O8 1325440   // vp_rot (4,1024,3,3)

// ws offsets (floats)
#define W1T 0
#define C1T 65536
#define SA1 131072
#define SA2 131328
#define WCIDX 131584  // 4*20000 ints
#define WM 211584     // 4 ints

#define FPS_CAP 6144
#define FPS_P2 8192
#define K3T 512
#define K3W 8
#define SLOTS 12
// dyn LDS floats: xs/ys/zs 3*6144 + SK 8192 + scm 48 + pvk 2*8*2
#define K3_LDS_BYTES ((18432 + 8192 + 48 + 32) * 4)

// ---------------- prep: transpose weights to k-major, bn scales ----------------
__global__ void k0_transpose(const float* __restrict__ w1, const float* __restrict__ c1w,
                             float* __restrict__ ws) {
  const int k = blockIdx.x, o = threadIdx.x;
  const float* src = blockIdx.y ? c1w : w1;
  float* dst = ws + (blockIdx.y ? C1T : W1T);
  dst[k * CH + o] = src[o * CH + k];
}

__global__ void k0_scales(const float* __restrict__ g1, const float* __restrict__ v1,
                          const float* __restrict__ g2, const float* __restrict__ v2,
                          float* __restrict__ ws) {
  int c = threadIdx.x;
  ws[SA1 + c] = g1[c] / sqrtf(v1[c] + 1e-5f);
  ws[SA2 + c] = g2[c] / sqrtf(v2[c] + 1e-5f);
}

// ---------------- fused GEMM1+BN+ReLU+GEMM2 -> objectness, graspness ----------------
__global__ __launch_bounds__(256) void k1_scores(
    const float* __restrict__ F, const float* __restrict__ Wt,
    const float* __restrict__ b1, const float* __restrict__ bm,
    const float* __restrict__ bbn, const float* __restrict__ sc,
    const float* __restrict__ W2, const float* __restrict__ b2,
    float* __restrict__ out) {
  __shared__ float smem[KC * 256 + KC * 64];
  float* Wl = smem;
  float* Fl = smem + KC * 256;
  const int tid = threadIdx.x;
  const int b = blockIdx.y;
  const int n0 = blockIdx.x * 64;
  const int cg = tid >> 3, pg = tid & 7;
  const bool tail = (n0 + 64 > NPTS);
  float acc[8][8];
#pragma unroll
  for (int i = 0; i < 8; ++i)
#pragma unroll
    for (int j = 0; j < 8; ++j) acc[i][j] = 0.f;

  for (int k0 = 0; k0 < CH; k0 += KC) {
    const float4* gW = (const float4*)(Wt + (size_t)k0 * 256);
    float4* sW = (float4*)Wl;
#pragma unroll
    for (int r = 0; r < 8; ++r) sW[r * 256 + tid] = gW[r * 256 + tid];
#pragma unroll
    for (int h = 0; h < 2; ++h) {
      int v = h * 256 + tid;
      int kk = v >> 4, q = v & 15;
      const float* src = F + ((size_t)b * CH + (k0 + kk)) * NPTS;
      if (!tail) {
        *(float4*)&Fl[kk * 64 + q * 4] = *(const float4*)&src[n0 + q * 4];
      } else {
#pragma unroll
        for (int e = 0; e < 4; ++e) {
          int n = n0 + q * 4 + e;
          Fl[kk * 64 + q * 4 + e] = src[n < NPTS ? n : NPTS - 1];
        }
      }
    }
    __syncthreads();
#pragma unroll 4
    for (int kk = 0; kk < KC; ++kk) {
      float4 t0 = *(const float4*)&Wl[kk * 256 + cg * 8];
      float4 t1 = *(const float4*)&Wl[kk * 256 + cg * 8 + 4];
      float4 t2 = *(const float4*)&Fl[kk * 64 + pg * 8];
      float4 t3 = *(const float4*)&Fl[kk * 64 + pg * 8 + 4];
      float w[8], f[8];
      w[0] = t0.x; w[1] = t0.y; w[2] = t0.z; w[3] = t0.w;
      w[4] = t1.x; w[5] = t1.y; w[6] = t1.z; w[7] = t1.w;
      f[0] = t2.x; f[1] = t2.y; f[2] = t2.z; f[3] = t2.w;
      f[4] = t3.x; f[5] = t3.y; f[6] = t3.z; f[7] = t3.w;
#pragma unroll
      for (int i = 0; i < 8; ++i)
#pragma unroll
        for (int j = 0; j < 8; ++j) acc[i][j] = fmaf(w[i], f[j], acc[i][j]);
    }
    __syncthreads();
  }

  float pr[3][8];
#pragma unroll
  for (int r = 0; r < 3; ++r)
#pragma unroll
    for (int j = 0; j < 8; ++j) pr[r][j] = 0.f;
#pragma unroll
  for (int i = 0; i < 8; ++i) {
    int c = cg * 8 + i;
    float bsv = b1[c], mv = bm[c], sv = sc[c], bv = bbn[c];
    float w20 = W2[c], w21 = W2[256 + c], w22 = W2[512 + c];
#pragma unroll
    for (int j = 0; j < 8; ++j) {
      float y = acc[i][j] + bsv;
      float h = (y - mv) * sv + bv;
      h = fmaxf(h, 0.f);
      pr[0][j] = fmaf(w20, h, pr[0][j]);
      pr[1][j] = fmaf(w21, h, pr[1][j]);
      pr[2][j] = fmaf(w22, h, pr[2][j]);
    }
  }
  float* ebuf = smem;
#pragma unroll
  for (int r = 0; r < 3; ++r)
#pragma unroll
    for (int j = 0; j < 8; ++j) ebuf[r * 2112 + (pg * 8 + j) * 33 + cg] = pr[r][j];
  __syncthreads();
  if (tid < 64) {
    int n = n0 + tid;
    if (n < NPTS) {
      float y[3];
#pragma unroll
      for (int r = 0; r < 3; ++r) {
        float s = 0.f;
        for (int g = 0; g < 32; ++g) s += ebuf[r * 2112 + tid * 33 + g];
        y[r] = s + b2[r];
      }
      out[O0 + (size_t)b * 2 * NPTS + n] = y[0];
      out[O0 + ((size_t)b * 2 + 1) * NPTS + n] = y[1];
      out[O1 + (size_t)b * NPTS + n] = y[2];
    }
  }
}

// ---------------- ordered stream compaction of masked indices ----------------
__global__ __launch_bounds__(1024) void k2_compact(const float* __restrict__ out,
                                                   int* __restrict__ cidx,
                                                   int* __restrict__ Mc) {
  __shared__ int wcnt[16];
  const int b = blockIdx.x;
  const int tid = threadIdx.x;
  const int wid = tid >> 6, lane = tid & 63;
  const float* o0 = out + O0 + (size_t)b * 2 * NPTS;
  const float* o1 = o0 + NPTS;
  const float* gg = out + O1 + (size_t)b * NPTS;
  int running = 0;
  for (int base = 0; base < NPTS; base += 1024) {
    int n = base + tid;
    bool m = false;
    if (n < NPTS) m = (o1[n] > o0[n]) && (gg[n] > 0.1f);
    unsigned long long bal = __ballot(m);
    if (lane == 0) wcnt[wid] = __popcll(bal);
    __syncthreads();
    int woff = 0, total = 0;
    for (int w = 0; w < 16; ++w) {
      int c = wcnt[w];
      if (w < wid) woff += c;
      total += c;
    }
    if (m) {
      int pos = running + woff + (int)__popcll(bal & ((1ull << lane) - 1ull));
      cidx[(size_t)b * NPTS + pos] = n;
    }
    running += total;
    __syncthreads();
  }
  if (tid == 0) Mc[b] = running;
}

// ---------------- DPP / shuffle reduction helpers ----------------
template <int CTRL>
__device__ __forceinline__ float dppf(float v) {
  return __int_as_float(__builtin_amdgcn_update_dpp(
      __float_as_int(v), __float_as_int(v), CTRL, 0xF, 0xF, false));
}
template <int CTRL>
__device__ __forceinline__ int dppi(int v) {
  return __builtin_amdgcn_update_dpp(v, v, CTRL, 0xF, 0xF, false);
}

// packed argmax combine: max value, tie -> min packed key ((orig<<13)|pos)
__device__ __forceinline__ void amax2pk(float& v, int& k, float ov, int ok) {
  bool tk = (ov > v) || (ov == v && ok < k);
  v = tk ? ov : v;
  k = tk ? ok : k;
}
// full 64-lane packed argmax; result in ALL lanes (validated r3/r4/r5)
__device__ __forceinline__ void wave_amax2pk(float& v, int& k) {
  amax2pk(v, k, dppf<0x121>(v), dppi<0x121>(k));
  amax2pk(v, k, dppf<0x122>(v), dppi<0x122>(k));
  amax2pk(v, k, dppf<0x124>(v), dppi<0x124>(k));
  amax2pk(v, k, dppf<0x128>(v), dppi<0x128>(k));
  amax2pk(v, k, __shfl_xor(v, 16, 64), __shfl_xor(k, 16, 64));
  amax2pk(v, k, __shfl_xor(v, 32, 64), __shfl_xor(k, 32, 64));
}
__device__ __forceinline__ float wave_fmin(float v) {
  v = fminf(v, dppf<0x121>(v));
  v = fminf(v, dppf<0x122>(v));
  v = fminf(v, dppf<0x124>(v));
  v = fminf(v, dppf<0x128>(v));
  v = fminf(v, __shfl_xor(v, 16, 64));
  v = fminf(v, __shfl_xor(v, 32, 64));
  return v;
}
__device__ __forceinline__ float wave_fmax(float v) {
  v = fmaxf(v, dppf<0x121>(v));
  v = fmaxf(v, dppf<0x122>(v));
  v = fmaxf(v, dppf<0x124>(v));
  v = fmaxf(v, dppf<0x128>(v));
  v = fmaxf(v, __shfl_xor(v, 16, 64));
  v = fmaxf(v, __shfl_xor(v, 32, 64));
  return v;
}

__device__ __forceinline__ unsigned p1by2(unsigned x) {
  x &= 0x3FFu;
  x = (x | (x << 16)) & 0x030000FFu;
  x = (x | (x << 8)) & 0x0300F00Fu;
  x = (x | (x << 4)) & 0x030C30C3u;
  x = (x | (x << 2)) & 0x09249249u;
  return x;
}

// ---------------- FPS: 8 waves, per-LANE 12-pt boxes, wave-skip + scalar scans ----------------
__global__ __launch_bounds__(K3T) void k3_fps(const float* __restrict__ sxyz,
                                              const int* __restrict__ cidx,
                                              const int* __restrict__ Mc,
                                              float* __restrict__ out) {
  extern __shared__ float sm[];
  float* xs = sm;                            // 6144, sorted order
  float* ys = sm + 6144;
  float* zs = sm + 12288;
  unsigned* SK = (unsigned*)(sm + 18432);    // 8192 sort keys
  float* scm = sm + 18432 + 8192;            // 48: block-bbox scratch
  float2* pvk = (float2*)(scm + 48);         // [2][8] wave (v, key)

  const int tid = threadIdx.x;
  const int lane = tid & 63, wid = tid >> 6;
  const int b = blockIdx.x;
  const int M = Mc[b];
  if (M > FPS_CAP) return;
  float* o3 = out + O3 + b * NS;
  if (M == 0) {
    o3[tid] = 0.f;
    o3[K3T + tid] = 0.f;
    return;
  }
  const int* ci = cidx + (size_t)b * NPTS;

  float px[SLOTS], py[SLOTS], pz[SLOTS], ds[SLOTS];
  int pk[SLOTS];

  // ---- phase 1: load compacted points (strided), thread bbox for Morton scaling ----
  float tmnx = 1e30f, tmny = 1e30f, tmnz = 1e30f;
  float tmxx = -1e30f, tmxy = -1e30f, tmxz = -1e30f;
#pragma unroll
  for (int s = 0; s < SLOTS; ++s) {
    int cpt = s * K3T + tid;
    if (cpt < M) {
      int orig = ci[cpt];
      const float* p = sxyz + ((size_t)b * NPTS + orig) * 3;
      px[s] = p[0]; py[s] = p[1]; pz[s] = p[2];
      tmnx = fminf(tmnx, px[s]); tmny = fminf(tmny, py[s]); tmnz = fminf(tmnz, pz[s]);
      tmxx = fmaxf(tmxx, px[s]); tmxy = fmaxf(tmxy, py[s]); tmxz = fmaxf(tmxz, pz[s]);
    } else {
      px[s] = 0.f; py[s] = 0.f; pz[s] = 0.f;
    }
  }
  // ---- phase 2: block bbox ----
  tmnx = wave_fmin(tmnx); tmny = wave_fmin(tmny); tmnz = wave_fmin(tmnz);
  tmxx = wave_fmax(tmxx); tmxy = wave_fmax(tmxy); tmxz = wave_fmax(tmxz);
  if (lane == 0) {
    scm[wid * 6 + 0] = tmnx; scm[wid * 6 + 1] = tmny; scm[wid * 6 + 2] = tmnz;
    scm[wid * 6 + 3] = tmxx; scm[wid * 6 + 4] = tmxy; scm[wid * 6 + 5] = tmxz;
  }
  __syncthreads();
  float mnx = 1e30f, mny = 1e30f, mnz = 1e30f, mxx = -1e30f, mxy = -1e30f, mxz = -1e30f;
  for (int w = 0; w < K3W; ++w) {
    mnx = fminf(mnx, scm[w * 6 + 0]); mny = fminf(mny, scm[w * 6 + 1]); mnz = fminf(mnz, scm[w * 6 + 2]);
    mxx = fmaxf(mxx, scm[w * 6 + 3]); mxy = fmaxf(mxy, scm[w * 6 + 4]); mxz = fmaxf(mxz, scm[w * 6 + 5]);
  }
  float sxk = 63.9f / fmaxf(mxx - mnx, 1e-9f);
  float syk = 63.9f / fmaxf(mxy - mny, 1e-9f);
  float szk = 63.9f / fmaxf(mxz - mnz, 1e-9f);

  // ---- phase 3: Morton keys ----
#pragma unroll
  for (int s = 0; s < SLOTS; ++s) {
    int cpt = s * K3T + tid;
    unsigned key = 0xFFFFFFFFu;
    if (cpt < M) {
      unsigned qx = (unsigned)fminf(fmaxf((px[s] - mnx) * sxk, 0.f), 63.f);
      unsigned qy = (unsigned)fminf(fmaxf((py[s] - mny) * syk, 0.f), 63.f);
      unsigned qz = (unsigned)fminf(fmaxf((pz[s] - mnz) * szk, 0.f), 63.f);
      unsigned mort = p1by2(qx) | (p1by2(qy) << 1) | (p1by2(qz) << 2);
      key = (mort << 13) | (unsigned)cpt;
    }
    SK[cpt] = key;
  }
  for (int p = 6144 + tid; p < FPS_P2; p += K3T) SK[p] = 0xFFFFFFFFu;

  // ---- phase 4: bitonic sort (8192 keys) ----
  for (int k = 2; k <= FPS_P2; k <<= 1) {
    for (int j = k >> 1; j > 0; j >>= 1) {
      __syncthreads();
#pragma unroll
      for (int v = 0; v < 16; ++v) {
        int i = v * K3T + tid;
        int ixj = i ^ j;
        if (ixj > i) {
          unsigned a = SK[i], bb = SK[ixj];
          bool up2 = ((i & k) == 0);
          if ((a > bb) == up2) { SK[i] = bb; SK[ixj] = a; }
        }
      }
    }
  }
  __syncthreads();

  // ---- phase 5: re-gather; LANE owns 12 CONTIGUOUS sorted points ----
#pragma unroll
  for (int s = 0; s < SLOTS; ++s) {
    int p = tid * SLOTS + s;
    unsigned key = SK[p];
    if (key != 0xFFFFFFFFu) {
      int pos = key & 8191;
      int orig = ci[pos];
      const float* q = sxyz + ((size_t)b * NPTS + orig) * 3;
      px[s] = q[0]; py[s] = q[1]; pz[s] = q[2];
      ds[s] = 1e10f;
      pk[s] = (orig << 13) | p;
    } else {
      px[s] = 0.f; py[s] = 0.f; pz[s] = 0.f;
      ds[s] = -1e30f;
      pk[s] = 0x7FFFFFFF;
    }
    xs[p] = px[s]; ys[p] = py[s]; zs[p] = pz[s];
  }

  // ---- phase 6: per-LANE bbox (registers only, no cross-lane) ----
  float lmnx = 1e30f, lmny = 1e30f, lmnz = 1e30f;
  float lmxx = -1e30f, lmxy = -1e30f, lmxz = -1e30f;
  bool anyreal = false;
#pragma unroll
  for (int s = 0; s < SLOTS; ++s) {
    bool real = (pk[s] != 0x7FFFFFFF);
    anyreal |= real;
    lmnx = fminf(lmnx, real ? px[s] : 1e30f); lmxx = fmaxf(lmxx, real ? px[s] : -1e30f);
    lmny = fminf(lmny, real ? py[s] : 1e30f); lmxy = fmaxf(lmxy, real ? py[s] : -1e30f);
    lmnz = fminf(lmnz, real ? pz[s] : 1e30f); lmxz = fmaxf(lmxz, real ? pz[s] : -1e30f);
  }
  const float lbcx = anyreal ? 0.5f * (lmnx + lmxx) : 1e30f;
  const float lbcy = anyreal ? 0.5f * (lmny + lmxy) : 1e30f;
  const float lbcz = anyreal ? 0.5f * (lmnz + lmxz) : 1e30f;
  const float lbhx = anyreal ? 0.5f * (lmxx - lmnx) + 1e-6f : 0.f;
  const float lbhy = anyreal ? 0.5f * (lmxy - lmny) + 1e-6f : 0.f;
  const float lbhz = anyreal ? 0.5f * (lmxz - lmnz) + 1e-6f : 0.f;

  // per-lane cached max dist; wave cached aggregate (wv,wk)
  float cav = anyreal ? 1e10f : -1e30f;
  float wv;
  int wk;
  {
    float v = -1e30f;
    int k = 0x7FFFFFFF;
#pragma unroll
    for (int s = 0; s < SLOTS; ++s) amax2pk(v, k, ds[s], pk[s]);
    wave_amax2pk(v, k);
    wv = v; wk = k;
  }

  // ---- init: center = first masked point ----
  int orig0 = ci[0];
  const float* fp0 = sxyz + ((size_t)b * NPTS + orig0) * 3;
  float cx = fp0[0], cy = fp0[1], cz = fp0[2];
  if (tid == 0) o3[0] = (float)orig0;
  int par = 0;

  for (int t = 1; t < NS; ++t) {
    // fine-grained exact prune test per LANE; wave updates iff any lane fires
    float ddx = fmaxf(fabsf(cx - lbcx) - lbhx, 0.f);
    float ddy = fmaxf(fabsf(cy - lbcy) - lbhy, 0.f);
    float ddz = fmaxf(fabsf(cz - lbcz) - lbhz, 0.f);
    float bd2 = ddx * ddx + ddy * ddy + ddz * ddz;
    bool upd = !(bd2 >= cav * 1.0001f + 1e-12f);
    if (__ballot(upd)) {  // wave-uniform branch
      float v = -1e30f;
      int k = 0x7FFFFFFF;
#pragma unroll
      for (int s = 0; s < SLOTS; ++s) {
        float dx = __fsub_rn(px[s], cx);
        float dy = __fsub_rn(py[s], cy);
        float dz = __fsub_rn(pz[s], cz);
        float d = __fadd_rn(__fadd_rn(__fmul_rn(dx, dx), __fmul_rn(dy, dy)), __fmul_rn(dz, dz));
        float nd = fminf(ds[s], d);
        ds[s] = nd;
        amax2pk(v, k, nd, pk[s]);
      }
      cav = v;  // lane's new max
      wave_amax2pk(v, k);
      wv = v; wk = k;
    }
    if (lane == 0) pvk[par * K3W + wid] = make_float2(wv, __int_as_float(wk));
    __syncthreads();
    // scalar broadcast scan of 8 wave aggregates (no cross-lane ops)
    float v = -3e38f;
    int k = 0x7FFFFFFF;
#pragma unroll
    for (int w = 0; w < K3W; ++w) {
      float2 e = pvk[par * K3W + w];
      amax2pk(v, k, e.x, __float_as_int(e.y));
    }
    int pos = k & 8191;
    if (tid == 0) o3[t] = (float)(k >> 13);
    cx = xs[pos]; cy = ys[pos]; cz = zs[pos];
    par ^= 1;
  }
}

// ---------------- FPS fallback for M > FPS_CAP: full-N, regs ----------------
__global__ __launch_bounds__(512) void k3b_fps(const float* __restrict__ sxyz,
                                               const int* __restrict__ Mc,
                                               float* __restrict__ out) {
  const int b = blockIdx.x;
  const int M = Mc[b];
  if (M <= FPS_CAP) return;
  const int tid = threadIdx.x;
  float* o3 = out + O3 + b * NS;
  const float* o0 = out + O0 + (size_t)b * 2 * NPTS;
  const float* o1 = o0 + NPTS;
  const float* gg = out + O1 + (size_t)b * NPTS;
  __shared__ float pd[2][8];
  __shared__ int pi[2][8];
  float px[40], py[40], pz[40], ds[40];
#pragma unroll
  for (int s = 0; s < 40; ++s) {
    int n = s * 512 + tid;
    if (n < NPTS) {
      const float* p = sxyz + ((size_t)b * NPTS + n) * 3;
      px[s] = p[0]; py[s] = p[1]; pz[s] = p[2];
      bool m = (o1[n] > o0[n]) && (gg[n] > 0.1f);
      ds[s] = m ? 1e10f : -1e10f;
    } else {
      px[s] = 0.f; py[s] = 0.f; pz[s] = 0.f; ds[s] = -1e30f;
    }
  }
  const int lane = tid & 63, wid = tid >> 6;
  int par = 0;
  float cx = 0.f, cy = 0.f, cz = 0.f;
  for (int t = 0; t < NS; ++t) {
    float best = -1e30f;
    int bi = 0x7FFFFFFF;
#pragma unroll
    for (int s = 0; s < 40; ++s) {
      float nd;
      if (t > 0) {
        float dx = __fsub_rn(px[s], cx);
        float dy = __fsub_rn(py[s], cy);
        float dz = __fsub_rn(pz[s], cz);
        float d = __fadd_rn(__fadd_rn(__fmul_rn(dx, dx), __fmul_rn(dy, dy)), __fmul_rn(dz, dz));
        nd = fminf(ds[s], d);
        ds[s] = nd;
      } else {
        nd = ds[s];
      }
      if (nd > best) { best = nd; bi = s * 512 + tid; }
    }
#pragma unroll
    for (int m = 1; m < 64; m <<= 1) {
      float od = __shfl_xor(best, m, 64);
      int oi = __shfl_xor(bi, m, 64);
      if (od > best || (od == best && oi < bi)) { best = od; bi = oi; }
    }
    if (lane == 0) { pd[par][wid] = best; pi[par][wid] = bi; }
    __syncthreads();
    float rd = pd[par][lane & 7];
    int ri = pi[par][lane & 7];
#pragma unroll
    for (int m = 1; m < 8; m <<= 1) {
      float od = __shfl_xor(rd, m, 64);
      int oi = __shfl_xor(ri, m, 64);
      if (od > rd || (od == rd && oi < ri)) { rd = od; ri = oi; }
    }
    const float* p = sxyz + ((size_t)b * NPTS + ri) * 3;
    cx = p[0]; cy = p[1]; cz = p[2];
    if (tid == 0) o3[t] = (float)ri;
    par ^= 1;
  }
}

// ---------------- gathers: xyz, features, graspness ----------------
__global__ __launch_bounds__(256) void k4a_gather(const float* __restrict__ sxyz,
                                                  const float* __restrict__ sfeat,
                                                  float* __restrict__ out) {
  const int b = blockIdx.y;
  const int i = blockIdx.x * 64 + (threadIdx.x & 63);
  const int grp = threadIdx.x >> 6;
  int idx = (int)out[O3 + b * NS + i];
  idx = idx < 0 ? 0 : (idx >= NPTS ? NPTS - 1 : idx);  // defensive clamp
  const float* fb = sfeat + (size_t)b * CH * NPTS;
  float* o4 = out + O4 + (size_t)b * CH * NS;
  for (int c = grp; c < CH; c += 4) o4[c * NS + i] = fb[(size_t)c * NPTS + idx];
  if (grp == 0) {
    const float* p = sxyz + ((size_t)b * NPTS + idx) * 3;
    float* o2 = out + O2 + ((size_t)b * NS + i) * 3;
    o2[0] = p[0]; o2[1] = p[1]; o2[2] = p[2];
    out[O5 + b * NS + i] = out[O1 + (size_t)b * NPTS + idx];
  }
}

// ---------------- fused GEMM3+BN+ReLU+GEMM4 -> vp_xyz ----------------
__global__ __launch_bounds__(256) void k4b_gemm(
    float* __restrict__ out, const float* __restrict__ Wt,
    const float* __restrict__ b1, const float* __restrict__ bm,
    const float* __restrict__ bbn, const float* __restrict__ sc,
    const float* __restrict__ W2, const float* __restrict__ b2) {
  __shared__ float smem[KC * 256 + KC * 64];
  float* Wl = smem;
  float* Fl = smem + KC * 256;
  const float* F = out + O4;
  const int tid = threadIdx.x;
  const int b = blockIdx.y;
  const int n0 = blockIdx.x * 64;
  const int cg = tid >> 3, pg = tid & 7;
  float acc[8][8];
#pragma unroll
  for (int i = 0; i < 8; ++i)
#pragma unroll
    for (int j = 0; j < 8; ++j) acc[i][j] = 0.f;

  for (int k0 = 0; k0 < CH; k0 += KC) {
    const float4* gW = (const float4*)(Wt + (size_t)k0 * 256);
    float4* sW = (float4*)Wl;
#pragma unroll
    for (int r = 0; r < 8; ++r) sW[r * 256 + tid] = gW[r * 256 + tid];
#pragma unroll
    for (int h = 0; h < 2; ++h) {
      int v = h * 256 + tid;
      int kk = v >> 4, q = v & 15;
      const float* src = F + ((size_t)b * CH + (k0 + kk)) * NS;
      *(float4*)&Fl[kk * 64 + q * 4] = *(const float4*)&src[n0 + q * 4];
    }
    __syncthreads();
#pragma unroll 4
    for (int kk = 0; kk < KC; ++kk) {
      float4 t0 = *(const float4*)&Wl[kk * 256 + cg * 8];
      float4 t1 = *(const float4*)&Wl[kk * 256 + cg * 8 + 4];
      float4 t2 = *(const float4*)&Fl[kk * 64 + pg * 8];
      float4 t3 = *(const float4*)&Fl[kk * 64 + pg * 8 + 4];
      float w[8], f[8];
      w[0] = t0.x; w[1] = t0.y; w[2] = t0.z; w[3] = t0.w;
      w[4] = t1.x; w[5] = t1.y; w[6] = t1.z; w[7] = t1.w;
      f[0] = t2.x; f[1] = t2.y; f[2] = t2.z; f[3] = t2.w;
      f[4] = t3.x; f[5] = t3.y; f[6] = t3.z; f[7] = t3.w;
#pragma unroll
      for (int i = 0; i < 8; ++i)
#pragma unroll
        for (int j = 0; j < 8; ++j) acc[i][j] = fmaf(w[i], f[j], acc[i][j]);
    }
    __syncthreads();
  }
  float pr[3][8];
#pragma unroll
  for (int r = 0; r < 3; ++r)
#pragma unroll
    for (int j = 0; j < 8; ++j) pr[r][j] = 0.f;
#pragma unroll
  for (int i = 0; i < 8; ++i) {
    int c = cg * 8 + i;
    float bsv = b1[c], mv = bm[c], sv = sc[c], bv = bbn[c];
    float w20 = W2[c], w21 = W2[256 + c], w22 = W2[512 + c];
#pragma unroll
    for (int j = 0; j < 8; ++j) {
      float y = acc[i][j] + bsv;
      float h = (y - mv) * sv + bv;
      h = fmaxf(h, 0.f);
      pr[0][j] = fmaf(w20, h, pr[0][j]);
      pr[1][j] = fmaf(w21, h, pr[1][j]);
      pr[2][j] = fmaf(w22, h, pr[2][j]);
    }
  }
  float* ebuf = smem;
#pragma unroll
  for (int r = 0; r < 3; ++r)
#pragma unroll
    for (int j = 0; j < 8; ++j) ebuf[r * 2112 + (pg * 8 + j) * 33 + cg] = pr[r][j];
  __syncthreads();
  if (tid < 64) {
    int n = n0 + tid;
    float y[3];
#pragma unroll
    for (int r = 0; r < 3; ++r) {
      float s = 0.f;
      for (int g = 0; g < 32; ++g) s += ebuf[r * 2112 + tid * 33 + g];
      y[r] = s + b2[r];
    }
    float* o6 = out + O6 + ((size_t)b * NS + n) * 3;
    o6[0] = y[0]; o6[1] = y[1]; o6[2] = y[2];
  }
}

// ---------------- views argmax + rotation matrices ----------------
__global__ __launch_bounds__(256) void k4d_views(float* __restrict__ out) {
  __shared__ float vx[NV], vy[NV], vz[NV], vn[NV];
  const int tid = threadIdx.x;
  for (int v = tid; v < NV; v += 256) {
    double phi = (sqrt(5.0) - 1.0) / 2.0;
    double z = (2.0 * (double)v + 1.0) / (double)NV - 1.0;
    double r = sqrt(fmax(1.0 - z * z, 0.0));
    double ang = 2.0 * 3.141592653589793 * (double)v * phi;
    float X = (float)(r * cos(ang));
    float Y = (float)(r * sin(ang));
    float Z = (float)z;
    vx[v] = X; vy[v] = Y; vz[v] = Z;
    vn[v] = sqrtf(__fadd_rn(__fadd_rn(__fmul_rn(X, X), __fmul_rn(Y, Y)), __fmul_rn(Z, Z)));
  }
  __syncthreads();
  const int b = blockIdx.y;
  const int i = blockIdx.x * 256 + tid;
  const float* vp = out + O6 + ((size_t)b * NS + i) * 3;
  float p0 = vp[0], p1 = vp[1], p2 = vp[2];
  float npt = sqrtf(__fadd_rn(__fadd_rn(__fmul_rn(p0, p0), __fmul_rn(p1, p1)), __fmul_rn(p2, p2)));
  float bv = -3.4e38f;
  int bvi = 0;
  for (int v = 0; v < NV; ++v) {
    float dot = __fadd_rn(__fadd_rn(__fmul_rn(vx[v], p0), __fmul_rn(vy[v], p1)), __fmul_rn(vz[v], p2));
    float den = fmaxf(__fmul_rn(vn[v], npt), 1e-8f);
    float val = dot / den;
    if (val > bv) { bv = val; bvi = v; }
  }
  out[O7 + b * NS + i] = (float)bvi;
  float t0 = -p0, t1 = -p1, t2 = -p2;
  float a0 = -t1, a1 = t0, a2 = 0.f;
  float ny = sqrtf(__fadd_rn(__fadd_rn(__fmul_rn(a0, a0), __fmul_rn(a1, a1)), __fmul_rn(a2, a2)));
  if (ny == 0.f) { a0 = 0.f; a1 = 1.f; a2 = 0.f; }
  float nx = sqrtf(__fadd_rn(__fadd_rn(__fmul_rn(t0, t0), __fmul_rn(t1, t1)), __fmul_rn(t2, t2)));
  float x0 = t0 / nx, x1 = t1 / nx, x2 = t2 / nx;
  float ny2 = sqrtf(__fadd_rn(__fadd_rn(__fmul_rn(a0, a0), __fmul_rn(a1, a1)), __fmul_rn(a2, a2)));
  float y0 = a0 / ny2, y1 = a1 / ny2, y2 = a2 / ny2;
  float z0 = __fsub_rn(__fmul_rn(x1, y2), __fmul_rn(x2, y1));
  float z1 = __fsub_rn(__fmul_rn(x2, y0), __fmul_rn(x0, y2));
  float z2 = __fsub_rn(__fmul_rn(x0, y1), __fmul_rn(x1, y0));
  float* R = out + O8 + ((size_t)b * NS + i) * 9;
  R[0] = x0; R[1] = y0; R[2] = z0;
  R[3] = x1; R[4] = y1; R[5] = z1;
  R[6] = x2; R[7] = y2; R[8] = z2;
}

extern "C" void kernel_launch(void* const* d_in, const int* in_sizes, int n_in,
                              void* d_out, int out_size, void* d_ws, size_t ws_size,
                              hipStream_t stream) {
  const float* sxyz = (const float*)d_in[0];
  const float* sfeat = (const float*)d_in[1];
  const float* gh_w1 = (const float*)d_in[2];
  const float* gh_b1 = (const float*)d_in[3];
  const float* gh_bn_g = (const float*)d_in[4];
  const float* gh_bn_b = (const float*)d_in[5];
  const float* gh_bn_m = (const float*)d_in[6];
  const float* gh_bn_v = (const float*)d_in[7];
  const float* gh_w2 = (const float*)d_in[8];
  const float* gh_b2 = (const float*)d_in[9];
  const float* c1_w = (const float*)d_in[10];
  const float* c1_b = (const float*)d_in[11];
  const float* bn1_g = (const float*)d_in[12];
  const float* bn1_b = (const float*)d_in[13];
  const float* bn1_m = (const float*)d_in[14];
  const float* bn1_v = (const float*)d_in[15];
  const float* c2_w = (const float*)d_in[16];
  const float* c2_b = (const float*)d_in[17];
  float* out = (float*)d_out;
  float* ws = (float*)d_ws;
  int* cidx = (int*)(ws + WCIDX);
  int* Mc = (int*)(ws + WM);

  hipLaunchKernelGGL(k0_transpose, dim3(CH, 2), dim3(CH), 0, stream, gh_w1, c1_w, ws);
  hipLaunchKernelGGL(k0_scales, dim3(1), dim3(CH), 0, stream, gh_bn_g, gh_bn_v, bn1_g, bn1_v, ws);
  hipLaunchKernelGGL(k1_scores, dim3((NPTS + 63) / 64, NB), dim3(256), 0, stream,
                     sfeat, ws + W1T, gh_b1, gh_bn_m, gh_bn_b, ws + SA1, gh_w2, gh_b2, out);
  hipLaunchKernelGGL(k2_compact, dim3(NB), dim3(1024), 0, stream, out, cidx, Mc);
  hipLaunchKernelGGL(k3_fps, dim3(NB), dim3(K3T), K3_LDS_BYTES, stream, sxyz, cidx, Mc, out);
  hipLaunchKernelGGL(k3b_fps, dim3(NB), dim3(512), 0, stream, sxyz, Mc, out);
  hipLaunchKernelGGL(k4a_gather, dim3(16, NB), dim3(256), 0, stream, sxyz, sfeat, out);
  hipLaunchKernelGGL(k4b_gemm, dim3(16, NB), dim3(256), 0, stream,
                     out, ws + C1T, c1_b, bn1_m, bn1_b, ws + SA2, c2_w, c2_b);
  hipLaunchKernelGGL(k4d_views, dim3(4, NB), dim3(256), 0, stream, out);
}

// Round 7
// 1316.405 us; speedup vs baseline: 1.7589x; 1.7589x over previous
//
#include <hip/hip_runtime.h>
#include <math.h>

#define NB 4
#define NPTS 20000
#define CH 256
#define NS 1024
#define NV 300
#define KC 32

// out offsets (floats)
#define O0 0         // objectness (4,2,20000)
#define O1 160000    // graspness (4,20000)
#define O2 240000    // graspable_xyz (4,1024,3)
#define O3 252288    // graspable_inds (4,1024)
#define O4 256384    // graspable_features (4,256,1024)
#define O5 1304960   // fp2_graspness (4,1024)
#define O6 1309056   // vp_xyz (4,1024,3)
#define O7 1321344   // top_view_inds (4,1024)
#define O8 1325440   // vp_rot (4,1024,3,3)

// ws offsets (floats)
#define W1T 0
#define C1T 65536
#define SA1 131072
#define SA2 131328
#define WCIDX 131584  // 4*20000 ints
#define WM 211584     // 4 ints

#define FPS_CAP 6144
#define FPS_P2 8192
#define SLOTS 6
// dyn LDS floats: xs/ys/zs 3*6144 + SK 8192 + scm 96 + pdv 16 + piv 16
#define K3_LDS_BYTES ((18432 + 8192 + 96 + 16 + 16) * 4)

// ---------------- prep: transpose weights to k-major, bn scales ----------------
__global__ void k0_transpose(const float* __restrict__ w1, const float* __restrict__ c1w,
                             float* __restrict__ ws) {
  const int k = blockIdx.x, o = threadIdx.x;
  const float* src = blockIdx.y ? c1w : w1;
  float* dst = ws + (blockIdx.y ? C1T : W1T);
  dst[k * CH + o] = src[o * CH + k];
}

__global__ void k0_scales(const float* __restrict__ g1, const float* __restrict__ v1,
                          const float* __restrict__ g2, const float* __restrict__ v2,
                          float* __restrict__ ws) {
  int c = threadIdx.x;
  ws[SA1 + c] = g1[c] / sqrtf(v1[c] + 1e-5f);
  ws[SA2 + c] = g2[c] / sqrtf(v2[c] + 1e-5f);
}

// ---------------- fused GEMM1+BN+ReLU+GEMM2 -> objectness, graspness ----------------
__global__ __launch_bounds__(256) void k1_scores(
    const float* __restrict__ F, const float* __restrict__ Wt,
    const float* __restrict__ b1, const float* __restrict__ bm,
    const float* __restrict__ bbn, const float* __restrict__ sc,
    const float* __restrict__ W2, const float* __restrict__ b2,
    float* __restrict__ out) {
  __shared__ float smem[KC * 256 + KC * 64];
  float* Wl = smem;
  float* Fl = smem + KC * 256;
  const int tid = threadIdx.x;
  const int b = blockIdx.y;
  const int n0 = blockIdx.x * 64;
  const int cg = tid >> 3, pg = tid & 7;
  const bool tail = (n0 + 64 > NPTS);
  float acc[8][8];
#pragma unroll
  for (int i = 0; i < 8; ++i)
#pragma unroll
    for (int j = 0; j < 8; ++j) acc[i][j] = 0.f;

  for (int k0 = 0; k0 < CH; k0 += KC) {
    const float4* gW = (const float4*)(Wt + (size_t)k0 * 256);
    float4* sW = (float4*)Wl;
#pragma unroll
    for (int r = 0; r < 8; ++r) sW[r * 256 + tid] = gW[r * 256 + tid];
#pragma unroll
    for (int h = 0; h < 2; ++h) {
      int v = h * 256 + tid;
      int kk = v >> 4, q = v & 15;
      const float* src = F + ((size_t)b * CH + (k0 + kk)) * NPTS;
      if (!tail) {
        *(float4*)&Fl[kk * 64 + q * 4] = *(const float4*)&src[n0 + q * 4];
      } else {
#pragma unroll
        for (int e = 0; e < 4; ++e) {
          int n = n0 + q * 4 + e;
          Fl[kk * 64 + q * 4 + e] = src[n < NPTS ? n : NPTS - 1];
        }
      }
    }
    __syncthreads();
#pragma unroll 4
    for (int kk = 0; kk < KC; ++kk) {
      float4 t0 = *(const float4*)&Wl[kk * 256 + cg * 8];
      float4 t1 = *(const float4*)&Wl[kk * 256 + cg * 8 + 4];
      float4 t2 = *(const float4*)&Fl[kk * 64 + pg * 8];
      float4 t3 = *(const float4*)&Fl[kk * 64 + pg * 8 + 4];
      float w[8], f[8];
      w[0] = t0.x; w[1] = t0.y; w[2] = t0.z; w[3] = t0.w;
      w[4] = t1.x; w[5] = t1.y; w[6] = t1.z; w[7] = t1.w;
      f[0] = t2.x; f[1] = t2.y; f[2] = t2.z; f[3] = t2.w;
      f[4] = t3.x; f[5] = t3.y; f[6] = t3.z; f[7] = t3.w;
#pragma unroll
      for (int i = 0; i < 8; ++i)
#pragma unroll
        for (int j = 0; j < 8; ++j) acc[i][j] = fmaf(w[i], f[j], acc[i][j]);
    }
    __syncthreads();
  }

  float pr[3][8];
#pragma unroll
  for (int r = 0; r < 3; ++r)
#pragma unroll
    for (int j = 0; j < 8; ++j) pr[r][j] = 0.f;
#pragma unroll
  for (int i = 0; i < 8; ++i) {
    int c = cg * 8 + i;
    float bsv = b1[c], mv = bm[c], sv = sc[c], bv = bbn[c];
    float w20 = W2[c], w21 = W2[256 + c], w22 = W2[512 + c];
#pragma unroll
    for (int j = 0; j < 8; ++j) {
      float y = acc[i][j] + bsv;
      float h = (y - mv) * sv + bv;
      h = fmaxf(h, 0.f);
      pr[0][j] = fmaf(w20, h, pr[0][j]);
      pr[1][j] = fmaf(w21, h, pr[1][j]);
      pr[2][j] = fmaf(w22, h, pr[2][j]);
    }
  }
  float* ebuf = smem;
#pragma unroll
  for (int r = 0; r < 3; ++r)
#pragma unroll
    for (int j = 0; j < 8; ++j) ebuf[r * 2112 + (pg * 8 + j) * 33 + cg] = pr[r][j];
  __syncthreads();
  if (tid < 64) {
    int n = n0 + tid;
    if (n < NPTS) {
      float y[3];
#pragma unroll
      for (int r = 0; r < 3; ++r) {
        float s = 0.f;
        for (int g = 0; g < 32; ++g) s += ebuf[r * 2112 + tid * 33 + g];
        y[r] = s + b2[r];
      }
      out[O0 + (size_t)b * 2 * NPTS + n] = y[0];
      out[O0 + ((size_t)b * 2 + 1) * NPTS + n] = y[1];
      out[O1 + (size_t)b * NPTS + n] = y[2];
    }
  }
}

// ---------------- ordered stream compaction of masked indices ----------------
__global__ __launch_bounds__(1024) void k2_compact(const float* __restrict__ out,
                                                   int* __restrict__ cidx,
                                                   int* __restrict__ Mc) {
  __shared__ int wcnt[16];
  const int b = blockIdx.x;
  const int tid = threadIdx.x;
  const int wid = tid >> 6, lane = tid & 63;
  const float* o0 = out + O0 + (size_t)b * 2 * NPTS;
  const float* o1 = o0 + NPTS;
  const float* gg = out + O1 + (size_t)b * NPTS;
  int running = 0;
  for (int base = 0; base < NPTS; base += 1024) {
    int n = base + tid;
    bool m = false;
    if (n < NPTS) m = (o1[n] > o0[n]) && (gg[n] > 0.1f);
    unsigned long long bal = __ballot(m);
    if (lane == 0) wcnt[wid] = __popcll(bal);
    __syncthreads();
    int woff = 0, total = 0;
    for (int w = 0; w < 16; ++w) {
      int c = wcnt[w];
      if (w < wid) woff += c;
      total += c;
    }
    if (m) {
      int pos = running + woff + (int)__popcll(bal & ((1ull << lane) - 1ull));
      cidx[(size_t)b * NPTS + pos] = n;
    }
    running += total;
    __syncthreads();
  }
  if (tid == 0) Mc[b] = running;
}

// ---------------- DPP / shuffle reduction helpers ----------------
template <int CTRL>
__device__ __forceinline__ float dppf(float v) {
  return __int_as_float(__builtin_amdgcn_update_dpp(
      __float_as_int(v), __float_as_int(v), CTRL, 0xF, 0xF, false));
}
template <int CTRL>
__device__ __forceinline__ int dppi(int v) {
  return __builtin_amdgcn_update_dpp(v, v, CTRL, 0xF, 0xF, false);
}

__device__ __forceinline__ float wave_fmin(float v) {
  v = fminf(v, dppf<0x121>(v));
  v = fminf(v, dppf<0x122>(v));
  v = fminf(v, dppf<0x124>(v));
  v = fminf(v, dppf<0x128>(v));
  v = fminf(v, __shfl_xor(v, 16, 64));
  v = fminf(v, __shfl_xor(v, 32, 64));
  return v;
}
__device__ __forceinline__ float wave_fmax(float v) {
  v = fmaxf(v, dppf<0x121>(v));
  v = fmaxf(v, dppf<0x122>(v));
  v = fmaxf(v, dppf<0x124>(v));
  v = fmaxf(v, dppf<0x128>(v));
  v = fmaxf(v, __shfl_xor(v, 16, 64));
  v = fmaxf(v, __shfl_xor(v, 32, 64));
  return v;
}
__device__ __forceinline__ int wave_imin(int v) {
  v = min(v, dppi<0x121>(v));
  v = min(v, dppi<0x122>(v));
  v = min(v, dppi<0x124>(v));
  v = min(v, dppi<0x128>(v));
  v = min(v, __shfl_xor(v, 16, 64));
  v = min(v, __shfl_xor(v, 32, 64));
  return v;
}

__device__ __forceinline__ unsigned p1by2(unsigned x) {
  x &= 0x3FFu;
  x = (x | (x << 16)) & 0x030000FFu;
  x = (x | (x << 8)) & 0x0300F00Fu;
  x = (x | (x << 4)) & 0x030C30C3u;
  x = (x | (x << 2)) & 0x09249249u;
  return x;
}

// ---------------- FPS: 16 waves, per-lane 6-pt boxes, value-first split reduction ----------------
__global__ __launch_bounds__(1024) void k3_fps(const float* __restrict__ sxyz,
                                               const int* __restrict__ cidx,
                                               const int* __restrict__ Mc,
                                               float* __restrict__ out) {
  extern __shared__ float sm[];
  float* xs = sm;                            // 6144, sorted order
  float* ys = sm + 6144;
  float* zs = sm + 12288;
  unsigned* SK = (unsigned*)(sm + 18432);    // 8192 sort keys
  float* scm = sm + 18432 + 8192;            // 96: block-bbox scratch
  float* pdv = scm + 96;                     // 16 wave value-maxima (16B aligned)
  int* piv = (int*)(pdv + 16);               // 16 wave candidate packed keys

  const int tid = threadIdx.x;
  const int lane = tid & 63, wid = tid >> 6;
  const int b = blockIdx.x;
  const int M = Mc[b];
  if (M > FPS_CAP) return;
  float* o3 = out + O3 + b * NS;
  if (M == 0) {
    o3[tid] = 0.f;
    return;
  }
  const int* ci = cidx + (size_t)b * NPTS;

  float px[SLOTS], py[SLOTS], pz[SLOTS], ds[SLOTS];
  int pk[SLOTS];

  // ---- phase 1: load compacted points (strided), thread bbox for Morton scaling ----
  float tmnx = 1e30f, tmny = 1e30f, tmnz = 1e30f;
  float tmxx = -1e30f, tmxy = -1e30f, tmxz = -1e30f;
#pragma unroll
  for (int s = 0; s < SLOTS; ++s) {
    int cpt = s * 1024 + tid;
    if (cpt < M) {
      int orig = ci[cpt];
      const float* p = sxyz + ((size_t)b * NPTS + orig) * 3;
      px[s] = p[0]; py[s] = p[1]; pz[s] = p[2];
      tmnx = fminf(tmnx, px[s]); tmny = fminf(tmny, py[s]); tmnz = fminf(tmnz, pz[s]);
      tmxx = fmaxf(tmxx, px[s]); tmxy = fmaxf(tmxy, py[s]); tmxz = fmaxf(tmxz, pz[s]);
    } else {
      px[s] = 0.f; py[s] = 0.f; pz[s] = 0.f;
    }
  }
  // ---- phase 2: block bbox ----
  tmnx = wave_fmin(tmnx); tmny = wave_fmin(tmny); tmnz = wave_fmin(tmnz);
  tmxx = wave_fmax(tmxx); tmxy = wave_fmax(tmxy); tmxz = wave_fmax(tmxz);
  if (lane == 0) {
    scm[wid * 6 + 0] = tmnx; scm[wid * 6 + 1] = tmny; scm[wid * 6 + 2] = tmnz;
    scm[wid * 6 + 3] = tmxx; scm[wid * 6 + 4] = tmxy; scm[wid * 6 + 5] = tmxz;
  }
  __syncthreads();
  float mnx = 1e30f, mny = 1e30f, mnz = 1e30f, mxx = -1e30f, mxy = -1e30f, mxz = -1e30f;
  for (int w = 0; w < 16; ++w) {
    mnx = fminf(mnx, scm[w * 6 + 0]); mny = fminf(mny, scm[w * 6 + 1]); mnz = fminf(mnz, scm[w * 6 + 2]);
    mxx = fmaxf(mxx, scm[w * 6 + 3]); mxy = fmaxf(mxy, scm[w * 6 + 4]); mxz = fmaxf(mxz, scm[w * 6 + 5]);
  }
  float sxk = 63.9f / fmaxf(mxx - mnx, 1e-9f);
  float syk = 63.9f / fmaxf(mxy - mny, 1e-9f);
  float szk = 63.9f / fmaxf(mxz - mnz, 1e-9f);

  // ---- phase 3: Morton keys ----
#pragma unroll
  for (int s = 0; s < SLOTS; ++s) {
    int cpt = s * 1024 + tid;
    unsigned key = 0xFFFFFFFFu;
    if (cpt < M) {
      unsigned qx = (unsigned)fminf(fmaxf((px[s] - mnx) * sxk, 0.f), 63.f);
      unsigned qy = (unsigned)fminf(fmaxf((py[s] - mny) * syk, 0.f), 63.f);
      unsigned qz = (unsigned)fminf(fmaxf((pz[s] - mnz) * szk, 0.f), 63.f);
      unsigned mort = p1by2(qx) | (p1by2(qy) << 1) | (p1by2(qz) << 2);
      key = (mort << 13) | (unsigned)cpt;
    }
    SK[cpt] = key;
  }
  SK[6 * 1024 + tid] = 0xFFFFFFFFu;
  SK[7 * 1024 + tid] = 0xFFFFFFFFu;

  // ---- phase 4: bitonic sort (8192 keys) ----
  for (int k = 2; k <= FPS_P2; k <<= 1) {
    for (int j = k >> 1; j > 0; j >>= 1) {
      __syncthreads();
#pragma unroll
      for (int v = 0; v < 8; ++v) {
        int i = v * 1024 + tid;
        int ixj = i ^ j;
        if (ixj > i) {
          unsigned a = SK[i], bb = SK[ixj];
          bool up2 = ((i & k) == 0);
          if ((a > bb) == up2) { SK[i] = bb; SK[ixj] = a; }
        }
      }
    }
  }
  __syncthreads();

  // ---- phase 5: re-gather; LANE owns 6 CONTIGUOUS sorted points ----
#pragma unroll
  for (int s = 0; s < SLOTS; ++s) {
    int p = tid * SLOTS + s;
    unsigned key = SK[p];
    if (key != 0xFFFFFFFFu) {
      int pos = key & 8191;
      int orig = ci[pos];
      const float* q = sxyz + ((size_t)b * NPTS + orig) * 3;
      px[s] = q[0]; py[s] = q[1]; pz[s] = q[2];
      ds[s] = 1e10f;
      pk[s] = (orig << 13) | p;
    } else {
      px[s] = 0.f; py[s] = 0.f; pz[s] = 0.f;
      ds[s] = -1e30f;
      pk[s] = 0x7FFFFFFF;
    }
    xs[p] = px[s]; ys[p] = py[s]; zs[p] = pz[s];
  }

  // ---- phase 6: per-LANE bbox (registers only) ----
  float lmnx = 1e30f, lmny = 1e30f, lmnz = 1e30f;
  float lmxx = -1e30f, lmxy = -1e30f, lmxz = -1e30f;
  bool anyreal = false;
#pragma unroll
  for (int s = 0; s < SLOTS; ++s) {
    bool real = (pk[s] != 0x7FFFFFFF);
    anyreal |= real;
    lmnx = fminf(lmnx, real ? px[s] : 1e30f); lmxx = fmaxf(lmxx, real ? px[s] : -1e30f);
    lmny = fminf(lmny, real ? py[s] : 1e30f); lmxy = fmaxf(lmxy, real ? py[s] : -1e30f);
    lmnz = fminf(lmnz, real ? pz[s] : 1e30f); lmxz = fmaxf(lmxz, real ? pz[s] : -1e30f);
  }
  const float lbcx = anyreal ? 0.5f * (lmnx + lmxx) : 1e30f;
  const float lbcy = anyreal ? 0.5f * (lmny + lmxy) : 1e30f;
  const float lbcz = anyreal ? 0.5f * (lmnz + lmxz) : 1e30f;
  const float lbhx = anyreal ? 0.5f * (lmxx - lmnx) + 1e-6f : 0.f;
  const float lbhy = anyreal ? 0.5f * (lmxy - lmny) + 1e-6f : 0.f;
  const float lbhz = anyreal ? 0.5f * (lmxz - lmnz) + 1e-6f : 0.f;

  // per-lane cached max (sentinel forces fire at t=1); wave cached value max
  float cav = anyreal ? 1e10f : -1e30f;
  float wv = wave_fmax(cav);

  // ---- init: center = first masked point ----
  int orig0 = ci[0];
  const float* fp0 = sxyz + ((size_t)b * NPTS + orig0) * 3;
  float cx = fp0[0], cy = fp0[1], cz = fp0[2];
  if (tid == 0) o3[0] = (float)orig0;

  for (int t = 1; t < NS; ++t) {
    // per-lane exact prune test; wave updates iff any lane fires
    float ddx = fmaxf(fabsf(cx - lbcx) - lbhx, 0.f);
    float ddy = fmaxf(fabsf(cy - lbcy) - lbhy, 0.f);
    float ddz = fmaxf(fabsf(cz - lbcz) - lbhz, 0.f);
    float bd2 = ddx * ddx + ddy * ddy + ddz * ddz;
    bool upd = !(bd2 >= cav * 1.0001f + 1e-12f);
    if (__ballot(upd)) {  // wave-uniform branch
      float v = -1e30f;
#pragma unroll
      for (int s = 0; s < SLOTS; ++s) {
        float dx = __fsub_rn(px[s], cx);
        float dy = __fsub_rn(py[s], cy);
        float dz = __fsub_rn(pz[s], cz);
        float d = __fadd_rn(__fadd_rn(__fmul_rn(dx, dx), __fmul_rn(dy, dy)), __fmul_rn(dz, dz));
        float nd = fminf(ds[s], d);
        ds[s] = nd;
        v = fmaxf(v, nd);
      }
      cav = v;                 // lane's new max
      wv = wave_fmax(v);       // value-only butterfly (6 ops)
    }
    if (lane == 0) pdv[wid] = wv;
    __syncthreads();
    // block value max: 16 floats, vector loads + tree
    float4 a0 = ((float4*)pdv)[0], a1 = ((float4*)pdv)[1];
    float4 a2 = ((float4*)pdv)[2], a3 = ((float4*)pdv)[3];
    float m0 = fmaxf(fmaxf(a0.x, a0.y), fmaxf(a0.z, a0.w));
    float m1 = fmaxf(fmaxf(a1.x, a1.y), fmaxf(a1.z, a1.w));
    float m2 = fmaxf(fmaxf(a2.x, a2.y), fmaxf(a2.z, a2.w));
    float m3 = fmaxf(fmaxf(a3.x, a3.y), fmaxf(a3.z, a3.w));
    float bv = fmaxf(fmaxf(m0, m1), fmaxf(m2, m3));
    // candidate extraction only on winner wave(s): min packed key among slots hitting bv
    int pkc = 0x7FFFFFFF;
    if (wv == bv) {  // wave-uniform (wv replicated)
#pragma unroll
      for (int s = 0; s < SLOTS; ++s)
        if (ds[s] == bv) pkc = min(pkc, pk[s]);
      pkc = wave_imin(pkc);
    }
    if (lane == 0) piv[wid] = pkc;
    __syncthreads();
    int4 b0 = ((int4*)piv)[0], b1 = ((int4*)piv)[1];
    int4 b2 = ((int4*)piv)[2], b3 = ((int4*)piv)[3];
    int n0 = min(min(b0.x, b0.y), min(b0.z, b0.w));
    int n1 = min(min(b1.x, b1.y), min(b1.z, b1.w));
    int n2 = min(min(b2.x, b2.y), min(b2.z, b2.w));
    int n3 = min(min(b3.x, b3.y), min(b3.z, b3.w));
    int wk = min(min(n0, n1), min(n2, n3));
    int pos = wk & 8191;
    if (tid == 0) o3[t] = (float)(wk >> 13);
    cx = xs[pos]; cy = ys[pos]; cz = zs[pos];
  }
}

// ---------------- FPS fallback for M > FPS_CAP: full-N, regs ----------------
__global__ __launch_bounds__(512) void k3b_fps(const float* __restrict__ sxyz,
                                               const int* __restrict__ Mc,
                                               float* __restrict__ out) {
  const int b = blockIdx.x;
  const int M = Mc[b];
  if (M <= FPS_CAP) return;
  const int tid = threadIdx.x;
  float* o3 = out + O3 + b * NS;
  const float* o0 = out + O0 + (size_t)b * 2 * NPTS;
  const float* o1 = o0 + NPTS;
  const float* gg = out + O1 + (size_t)b * NPTS;
  __shared__ float pd[2][8];
  __shared__ int pi[2][8];
  float px[40], py[40], pz[40], ds[40];
#pragma unroll
  for (int s = 0; s < 40; ++s) {
    int n = s * 512 + tid;
    if (n < NPTS) {
      const float* p = sxyz + ((size_t)b * NPTS + n) * 3;
      px[s] = p[0]; py[s] = p[1]; pz[s] = p[2];
      bool m = (o1[n] > o0[n]) && (gg[n] > 0.1f);
      ds[s] = m ? 1e10f : -1e10f;
    } else {
      px[s] = 0.f; py[s] = 0.f; pz[s] = 0.f; ds[s] = -1e30f;
    }
  }
  const int lane = tid & 63, wid = tid >> 6;
  int par = 0;
  float cx = 0.f, cy = 0.f, cz = 0.f;
  for (int t = 0; t < NS; ++t) {
    float best = -1e30f;
    int bi = 0x7FFFFFFF;
#pragma unroll
    for (int s = 0; s < 40; ++s) {
      float nd;
      if (t > 0) {
        float dx = __fsub_rn(px[s], cx);
        float dy = __fsub_rn(py[s], cy);
        float dz = __fsub_rn(pz[s], cz);
        float d = __fadd_rn(__fadd_rn(__fmul_rn(dx, dx), __fmul_rn(dy, dy)), __fmul_rn(dz, dz));
        nd = fminf(ds[s], d);
        ds[s] = nd;
      } else {
        nd = ds[s];
      }
      if (nd > best) { best = nd; bi = s * 512 + tid; }
    }
#pragma unroll
    for (int m = 1; m < 64; m <<= 1) {
      float od = __shfl_xor(best, m, 64);
      int oi = __shfl_xor(bi, m, 64);
      if (od > best || (od == best && oi < bi)) { best = od; bi = oi; }
    }
    if (lane == 0) { pd[par][wid] = best; pi[par][wid] = bi; }
    __syncthreads();
    float rd = pd[par][lane & 7];
    int ri = pi[par][lane & 7];
#pragma unroll
    for (int m = 1; m < 8; m <<= 1) {
      float od = __shfl_xor(rd, m, 64);
      int oi = __shfl_xor(ri, m, 64);
      if (od > rd || (od == rd && oi < ri)) { rd = od; ri = oi; }
    }
    const float* p = sxyz + ((size_t)b * NPTS + ri) * 3;
    cx = p[0]; cy = p[1]; cz = p[2];
    if (tid == 0) o3[t] = (float)ri;
    par ^= 1;
  }
}

// ---------------- gathers: xyz, features, graspness ----------------
__global__ __launch_bounds__(256) void k4a_gather(const float* __restrict__ sxyz,
                                                  const float* __restrict__ sfeat,
                                                  float* __restrict__ out) {
  const int b = blockIdx.y;
  const int i = blockIdx.x * 64 + (threadIdx.x & 63);
  const int grp = threadIdx.x >> 6;
  int idx = (int)out[O3 + b * NS + i];
  idx = idx < 0 ? 0 : (idx >= NPTS ? NPTS - 1 : idx);  // defensive clamp
  const float* fb = sfeat + (size_t)b * CH * NPTS;
  float* o4 = out + O4 + (size_t)b * CH * NS;
  for (int c = grp; c < CH; c += 4) o4[c * NS + i] = fb[(size_t)c * NPTS + idx];
  if (grp == 0) {
    const float* p = sxyz + ((size_t)b * NPTS + idx) * 3;
    float* o2 = out + O2 + ((size_t)b * NS + i) * 3;
    o2[0] = p[0]; o2[1] = p[1]; o2[2] = p[2];
    out[O5 + b * NS + i] = out[O1 + (size_t)b * NPTS + idx];
  }
}

// ---------------- fused GEMM3+BN+ReLU+GEMM4 -> vp_xyz ----------------
__global__ __launch_bounds__(256) void k4b_gemm(
    float* __restrict__ out, const float* __restrict__ Wt,
    const float* __restrict__ b1, const float* __restrict__ bm,
    const float* __restrict__ bbn, const float* __restrict__ sc,
    const float* __restrict__ W2, const float* __restrict__ b2) {
  __shared__ float smem[KC * 256 + KC * 64];
  float* Wl = smem;
  float* Fl = smem + KC * 256;
  const float* F = out + O4;
  const int tid = threadIdx.x;
  const int b = blockIdx.y;
  const int n0 = blockIdx.x * 64;
  const int cg = tid >> 3, pg = tid & 7;
  float acc[8][8];
#pragma unroll
  for (int i = 0; i < 8; ++i)
#pragma unroll
    for (int j = 0; j < 8; ++j) acc[i][j] = 0.f;

  for (int k0 = 0; k0 < CH; k0 += KC) {
    const float4* gW = (const float4*)(Wt + (size_t)k0 * 256);
    float4* sW = (float4*)Wl;
#pragma unroll
    for (int r = 0; r < 8; ++r) sW[r * 256 + tid] = gW[r * 256 + tid];
#pragma unroll
    for (int h = 0; h < 2; ++h) {
      int v = h * 256 + tid;
      int kk = v >> 4, q = v & 15;
      const float* src = F + ((size_t)b * CH + (k0 + kk)) * NS;
      *(float4*)&Fl[kk * 64 + q * 4] = *(const float4*)&src[n0 + q * 4];
    }
    __syncthreads();
#pragma unroll 4
    for (int kk = 0; kk < KC; ++kk) {
      float4 t0 = *(const float4*)&Wl[kk * 256 + cg * 8];
      float4 t1 = *(const float4*)&Wl[kk * 256 + cg * 8 + 4];
      float4 t2 = *(const float4*)&Fl[kk * 64 + pg * 8];
      float4 t3 = *(const float4*)&Fl[kk * 64 + pg * 8 + 4];
      float w[8], f[8];
      w[0] = t0.x; w[1] = t0.y; w[2] = t0.z; w[3] = t0.w;
      w[4] = t1.x; w[5] = t1.y; w[6] = t1.z; w[7] = t1.w;
      f[0] = t2.x; f[1] = t2.y; f[2] = t2.z; f[3] = t2.w;
      f[4] = t3.x; f[5] = t3.y; f[6] = t3.z; f[7] = t3.w;
#pragma unroll
      for (int i = 0; i < 8; ++i)
#pragma unroll
        for (int j = 0; j < 8; ++j) acc[i][j] = fmaf(w[i], f[j], acc[i][j]);
    }
    __syncthreads();
  }
  float pr[3][8];
#pragma unroll
  for (int r = 0; r < 3; ++r)
#pragma unroll
    for (int j = 0; j < 8; ++j) pr[r][j] = 0.f;
#pragma unroll
  for (int i = 0; i < 8; ++i) {
    int c = cg * 8 + i;
    float bsv = b1[c], mv = bm[c], sv = sc[c], bv = bbn[c];
    float w20 = W2[c], w21 = W2[256 + c], w22 = W2[512 + c];
#pragma unroll
    for (int j = 0; j < 8; ++j) {
      float y = acc[i][j] + bsv;
      float h = (y - mv) * sv + bv;
      h = fmaxf(h, 0.f);
      pr[0][j] = fmaf(w20, h, pr[0][j]);
      pr[1][j] = fmaf(w21, h, pr[1][j]);
      pr[2][j] = fmaf(w22, h, pr[2][j]);
    }
  }
  float* ebuf = smem;
#pragma unroll
  for (int r = 0; r < 3; ++r)
#pragma unroll
    for (int j = 0; j < 8; ++j) ebuf[r * 2112 + (pg * 8 + j) * 33 + cg] = pr[r][j];
  __syncthreads();
  if (tid < 64) {
    int n = n0 + tid;
    float y[3];
#pragma unroll
    for (int r = 0; r < 3; ++r) {
      float s = 0.f;
      for (int g = 0; g < 32; ++g) s += ebuf[r * 2112 + tid * 33 + g];
      y[r] = s + b2[r];
    }
    float* o6 = out + O6 + ((size_t)b * NS + n) * 3;
    o6[0] = y[0]; o6[1] = y[1]; o6[2] = y[2];
  }
}

// ---------------- views argmax + rotation matrices ----------------
__global__ __launch_bounds__(256) void k4d_views(float* __restrict__ out) {
  __shared__ float vx[NV], vy[NV], vz[NV], vn[NV];
  const int tid = threadIdx.x;
  for (int v = tid; v < NV; v += 256) {
    double phi = (sqrt(5.0) - 1.0) / 2.0;
    double z = (2.0 * (double)v + 1.0) / (double)NV - 1.0;
    double r = sqrt(fmax(1.0 - z * z, 0.0));
    double ang = 2.0 * 3.141592653589793 * (double)v * phi;
    float X = (float)(r * cos(ang));
    float Y = (float)(r * sin(ang));
    float Z = (float)z;
    vx[v] = X; vy[v] = Y; vz[v] = Z;
    vn[v] = sqrtf(__fadd_rn(__fadd_rn(__fmul_rn(X, X), __fmul_rn(Y, Y)), __fmul_rn(Z, Z)));
  }
  __syncthreads();
  const int b = blockIdx.y;
  const int i = blockIdx.x * 256 + tid;
  const float* vp = out + O6 + ((size_t)b * NS + i) * 3;
  float p0 = vp[0], p1 = vp[1], p2 = vp[2];
  float npt = sqrtf(__fadd_rn(__fadd_rn(__fmul_rn(p0, p0), __fmul_rn(p1, p1)), __fmul_rn(p2, p2)));
  float bv = -3.4e38f;
  int bvi = 0;
  for (int v = 0; v < NV; ++v) {
    float dot = __fadd_rn(__fadd_rn(__fmul_rn(vx[v], p0), __fmul_rn(vy[v], p1)), __fmul_rn(vz[v], p2));
    float den = fmaxf(__fmul_rn(vn[v], npt), 1e-8f);
    float val = dot / den;
    if (val > bv) { bv = val; bvi = v; }
  }
  out[O7 + b * NS + i] = (float)bvi;
  float t0 = -p0, t1 = -p1, t2 = -p2;
  float a0 = -t1, a1 = t0, a2 = 0.f;
  float ny = sqrtf(__fadd_rn(__fadd_rn(__fmul_rn(a0, a0), __fmul_rn(a1, a1)), __fmul_rn(a2, a2)));
  if (ny == 0.f) { a0 = 0.f; a1 = 1.f; a2 = 0.f; }
  float nx = sqrtf(__fadd_rn(__fadd_rn(__fmul_rn(t0, t0), __fmul_rn(t1, t1)), __fmul_rn(t2, t2)));
  float x0 = t0 / nx, x1 = t1 / nx, x2 = t2 / nx;
  float ny2 = sqrtf(__fadd_rn(__fadd_rn(__fmul_rn(a0, a0), __fmul_rn(a1, a1)), __fmul_rn(a2, a2)));
  float y0 = a0 / ny2, y1 = a1 / ny2, y2 = a2 / ny2;
  float z0 = __fsub_rn(__fmul_rn(x1, y2), __fmul_rn(x2, y1));
  float z1 = __fsub_rn(__fmul_rn(x2, y0), __fmul_rn(x0, y2));
  float z2 = __fsub_rn(__fmul_rn(x0, y1), __fmul_rn(x1, y0));
  float* R = out + O8 + ((size_t)b * NS + i) * 9;
  R[0] = x0; R[1] = y0; R[2] = z0;
  R[3] = x1; R[4] = y1; R[5] = z1;
  R[6] = x2; R[7] = y2; R[8] = z2;
}

extern "C" void kernel_launch(void* const* d_in, const int* in_sizes, int n_in,
                              void* d_out, int out_size, void* d_ws, size_t ws_size,
                              hipStream_t stream) {
  const float* sxyz = (const float*)d_in[0];
  const float* sfeat = (const float*)d_in[1];
  const float* gh_w1 = (const float*)d_in[2];
  const float* gh_b1 = (const float*)d_in[3];
  const float* gh_bn_g = (const float*)d_in[4];
  const float* gh_bn_b = (const float*)d_in[5];
  const float* gh_bn_m = (const float*)d_in[6];
  const float* gh_bn_v = (const float*)d_in[7];
  const float* gh_w2 = (const float*)d_in[8];
  const float* gh_b2 = (const float*)d_in[9];
  const float* c1_w = (const float*)d_in[10];
  const float* c1_b = (const float*)d_in[11];
  const float* bn1_g = (const float*)d_in[12];
  const float* bn1_b = (const float*)d_in[13];
  const float* bn1_m = (const float*)d_in[14];
  const float* bn1_v = (const float*)d_in[15];
  const float* c2_w = (const float*)d_in[16];
  const float* c2_b = (const float*)d_in[17];
  float* out = (float*)d_out;
  float* ws = (float*)d_ws;
  int* cidx = (int*)(ws + WCIDX);
  int* Mc = (int*)(ws + WM);

  hipLaunchKernelGGL(k0_transpose, dim3(CH, 2), dim3(CH), 0, stream, gh_w1, c1_w, ws);
  hipLaunchKernelGGL(k0_scales, dim3(1), dim3(CH), 0, stream, gh_bn_g, gh_bn_v, bn1_g, bn1_v, ws);
  hipLaunchKernelGGL(k1_scores, dim3((NPTS + 63) / 64, NB), dim3(256), 0, stream,
                     sfeat, ws + W1T, gh_b1, gh_bn_m, gh_bn_b, ws + SA1, gh_w2, gh_b2, out);
  hipLaunchKernelGGL(k2_compact, dim3(NB), dim3(1024), 0, stream, out, cidx, Mc);
  hipLaunchKernelGGL(k3_fps, dim3(NB), dim3(1024), K3_LDS_BYTES, stream, sxyz, cidx, Mc, out);
  hipLaunchKernelGGL(k3b_fps, dim3(NB), dim3(512), 0, stream, sxyz, Mc, out);
  hipLaunchKernelGGL(k4a_gather, dim3(16, NB), dim3(256), 0, stream, sxyz, sfeat, out);
  hipLaunchKernelGGL(k4b_gemm, dim3(16, NB), dim3(256), 0, stream,
                     out, ws + C1T, c1_b, bn1_m, bn1_b, ws + SA2, c2_w, c2_b);
  hipLaunchKernelGGL(k4d_views, dim3(4, NB), dim3(256), 0, stream, out);
}